// Round 4
// baseline (80.652 us; speedup 1.0000x reference)
//
#include <hip/hip_runtime.h>

// DescLayer fused kernel for MI355X (gfx950) — round 3 (resubmit; round 3
// hit a GPU-acquisition timeout, no data).
// out[b,s,i] = res[b,s,i] + Nk[b,s,i]
//   ln   = LayerNorm(x) * gamma + beta          (biased var, eps inside sqrt)
//   xp   = ln @ M^T ; res = ln @ R^T            (M,R are [out,in] row-major)
//   Nk_i = sum_{j,g} P[i,j,g] * xp[j] * cos(2*pi*k / periods[i,j,g])
//
// Round-2 post-mortem: kernel ~39 us (plus ~40 us harness ws-fill floor in
// dur_us). 42 cyc/instr => stall pathology, suspect scratch from
// address-taken float4 indexing ((float*)&p0)[e] (rule #20). This round:
//  - Phase C uses ONLY explicit .x/.y/.z/.w component access (no scratch risk)
//  - 4 rows per block, i-dim split in half across blocks: P/periods traffic
//    halves (64 MB total), rcp(p) amortized over 4 rows, still 2 blocks/CU.
//  - native revolutions path: cos(2*pi*k/p) = v_cos(v_fract(k * v_rcp(p))).

constexpr int BATCH = 2;
constexpr int SEQ   = 512;
constexpr int DIM   = 64;
constexpr int NB    = 8;
constexpr int ROWS  = BATCH * SEQ;
constexpr int RPB   = 4;               // rows per block
constexpr int IHALF = 32;              // outputs per block (i-split of 2)
constexpr float LN_EPS = 1e-5f;

__global__ __launch_bounds__(256) void desc_fused(
    const float* __restrict__ x,
    const int*   __restrict__ kk,
    const float* __restrict__ M,
    const float* __restrict__ R,
    const float* __restrict__ P,
    const float* __restrict__ gamma,
    const float* __restrict__ beta,
    const float* __restrict__ periods,
    float* __restrict__ out)
{
    const int rg = blockIdx.x >> 1;      // row group (4 rows)
    const int ih = blockIdx.x & 1;       // which half of i-space
    const int r0 = rg * RPB;
    const int t  = threadIdx.x;          // 0..255

    __shared__ float ln_s [RPB][DIM];
    __shared__ float xp_s [RPB][DIM];
    __shared__ float res_s[RPB][IHALF];

    // ---- Phase A: LayerNorm, 4 rows (one wave per row) ----
    {
        const int rr   = t >> 6;         // 0..3
        const int lane = t & 63;
        float xv = x[(r0 + rr) * DIM + lane];
        float s1 = xv, s2 = xv * xv;
        #pragma unroll
        for (int off = 32; off > 0; off >>= 1) {
            s1 += __shfl_xor(s1, off, 64);
            s2 += __shfl_xor(s2, off, 64);
        }
        float mu  = s1 * (1.0f / DIM);
        float var = s2 * (1.0f / DIM) - mu * mu;   // biased variance
        ln_s[rr][lane] = (xv - mu) * rsqrtf(var + LN_EPS) * gamma[lane] + beta[lane];
    }
    __syncthreads();

    // ---- Phase B1: xp[rr][o] = dot(M[o,:], ln[rr,:]) — all 256 threads ----
    {
        const int rr = t >> 6;
        const int o  = t & 63;
        const float4* W4 = reinterpret_cast<const float4*>(M + o * DIM);
        const float4* L4 = reinterpret_cast<const float4*>(ln_s[rr]);
        float acc = 0.f;
        #pragma unroll
        for (int j4 = 0; j4 < DIM / 4; ++j4) {
            float4 w = W4[j4];
            float4 l = L4[j4];
            acc += w.x * l.x + w.y * l.y + w.z * l.z + w.w * l.w;
        }
        xp_s[rr][o] = acc;
    }
    // ---- Phase B2: res[rr][ol] = dot(R[ih*32+ol,:], ln[rr,:]) — 128 threads ----
    if (t < RPB * IHALF) {
        const int rr = t >> 5;
        const int ol = t & 31;
        const float4* W4 = reinterpret_cast<const float4*>(R + (ih * IHALF + ol) * DIM);
        const float4* L4 = reinterpret_cast<const float4*>(ln_s[rr]);
        float acc = 0.f;
        #pragma unroll
        for (int j4 = 0; j4 < DIM / 4; ++j4) {
            float4 w = W4[j4];
            float4 l = L4[j4];
            acc += w.x * l.x + w.y * l.y + w.z * l.z + w.w * l.w;
        }
        res_s[rr][ol] = acc;
    }
    __syncthreads();

    // ---- Phase C: Nk for 4 rows over i in [ih*32, ih*32+32).
    //      i_local = t>>3 (32 values), part = t&7; j = jj*8 + part. ----
    const int i_local = t >> 3;
    const int part    = t & 7;
    const int i_glob  = ih * IHALF + i_local;

    const float kf0 = (float)kk[r0];
    const float kf1 = (float)kk[r0 + 1];
    const float kf2 = (float)kk[r0 + 2];
    const float kf3 = (float)kk[r0 + 3];

    float acc0 = 0.f, acc1 = 0.f, acc2 = 0.f, acc3 = 0.f;

    #pragma unroll 2
    for (int jj = 0; jj < 8; ++jj) {
        const int j    = jj * 8 + part;
        const int base = (i_glob * DIM + j) * NB;   // float offset, 32B aligned
        const float4 p0 = *reinterpret_cast<const float4*>(P + base);
        const float4 p1 = *reinterpret_cast<const float4*>(P + base + 4);
        const float4 q0 = *reinterpret_cast<const float4*>(periods + base);
        const float4 q1 = *reinterpret_cast<const float4*>(periods + base + 4);

        float s0 = 0.f, s1 = 0.f, s2 = 0.f, s3 = 0.f;

        #define DESC_TERM(PE, QE)                                               \
        {                                                                       \
            const float rp_ = __builtin_amdgcn_rcpf(QE);                        \
            s0 = fmaf(PE, __builtin_amdgcn_cosf(__builtin_amdgcn_fractf(kf0 * rp_)), s0); \
            s1 = fmaf(PE, __builtin_amdgcn_cosf(__builtin_amdgcn_fractf(kf1 * rp_)), s1); \
            s2 = fmaf(PE, __builtin_amdgcn_cosf(__builtin_amdgcn_fractf(kf2 * rp_)), s2); \
            s3 = fmaf(PE, __builtin_amdgcn_cosf(__builtin_amdgcn_fractf(kf3 * rp_)), s3); \
        }
        DESC_TERM(p0.x, q0.x)
        DESC_TERM(p0.y, q0.y)
        DESC_TERM(p0.z, q0.z)
        DESC_TERM(p0.w, q0.w)
        DESC_TERM(p1.x, q1.x)
        DESC_TERM(p1.y, q1.y)
        DESC_TERM(p1.z, q1.z)
        DESC_TERM(p1.w, q1.w)
        #undef DESC_TERM

        acc0 = fmaf(xp_s[0][j], s0, acc0);
        acc1 = fmaf(xp_s[1][j], s1, acc1);
        acc2 = fmaf(xp_s[2][j], s2, acc2);
        acc3 = fmaf(xp_s[3][j], s3, acc3);
    }

    // combine the 8 j-partials per output (lanes 8*i_local .. +7, same wave)
    #pragma unroll
    for (int off = 1; off < 8; off <<= 1) {
        acc0 += __shfl_xor(acc0, off, 64);
        acc1 += __shfl_xor(acc1, off, 64);
        acc2 += __shfl_xor(acc2, off, 64);
        acc3 += __shfl_xor(acc3, off, 64);
    }

    if (part < RPB) {
        const float accp = (part == 0) ? acc0 : (part == 1) ? acc1
                         : (part == 2) ? acc2 : acc3;
        out[(r0 + part) * DIM + i_glob] = res_s[part][i_local] + accp;
    }
}

extern "C" void kernel_launch(void* const* d_in, const int* in_sizes, int n_in,
                              void* d_out, int out_size, void* d_ws, size_t ws_size,
                              hipStream_t stream)
{
    const float* x       = (const float*)d_in[0];
    const int*   kk      = (const int*)  d_in[1];
    const float* M       = (const float*)d_in[2];
    const float* R       = (const float*)d_in[3];
    const float* P       = (const float*)d_in[4];
    const float* gamma   = (const float*)d_in[5];
    const float* beta    = (const float*)d_in[6];
    const float* periods = (const float*)d_in[7];
    float* out = (float*)d_out;

    desc_fused<<<(ROWS / RPB) * 2, 256, 0, stream>>>(x, kk, M, R, P, gamma, beta, periods, out);
}